// Round 1
// baseline (221.550 us; speedup 1.0000x reference)
//
#include <hip/hip_runtime.h>
#include <math.h>

#define NB 16
#define DIN 512
#define TT 4096
#define DCB 8
#define KC 1024

// ws layout (floats):
// [0,4096)      w_inT[d][c]   (transposed, 32B rows for s_load_dwordx8)
// [4096,8192)   w_out[o][c]
// [8192,9216)   cb2[k] = sum_c cb[k,c]^2
// [9216,10240)  per-block commit partials (1024)

__global__ __launch_bounds__(512) void vq_setup(
    const float* __restrict__ in_v, const float* __restrict__ in_g,
    const float* __restrict__ out_v, const float* __restrict__ out_g,
    const float* __restrict__ cb, float* __restrict__ ws)
{
    int tid = threadIdx.x;
    float* w_inT = ws;
    float* w_out = ws + 4096;
    float* cb2   = ws + 8192;

    // --- w_in: 8 rows of 512; one wave per row ---
    {
        int c    = tid >> 6;   // 0..7
        int lane = tid & 63;
        const float* v = in_v + c * DIN;
        float s = 0.f;
        #pragma unroll
        for (int i = 0; i < DIN; i += 64) {
            float x = v[i + lane];
            s += x * x;
        }
        #pragma unroll
        for (int off = 32; off > 0; off >>= 1) s += __shfl_xor(s, off, 64);
        float sq = sqrtf(s);
        float g  = in_g[c];
        #pragma unroll
        for (int i = 0; i < DIN; i += 64) {
            int d = i + lane;
            w_inT[d * DCB + c] = (g * v[d]) / sq;
        }
    }
    // --- w_out: 512 rows of 8; one thread per row ---
    {
        int o = tid;
        const float* v = out_v + o * DCB;
        float s = 0.f;
        #pragma unroll
        for (int c = 0; c < DCB; ++c) s += v[c] * v[c];
        float sq = sqrtf(s);
        float g  = out_g[o];
        #pragma unroll
        for (int c = 0; c < DCB; ++c) w_out[o * DCB + c] = (g * v[c]) / sq;
    }
    // --- cb2 ---
    for (int k = tid; k < KC; k += 512) {
        const float* r = cb + k * DCB;
        float s = 0.f;
        #pragma unroll
        for (int c = 0; c < DCB; ++c) s += r[c] * r[c];
        cb2[k] = s;
    }
}

__global__ __launch_bounds__(64) void vq_main(
    const float* __restrict__ z, const float* __restrict__ in_b,
    const float* __restrict__ out_b, const float* __restrict__ cb,
    const float* __restrict__ ws, float* __restrict__ ws_commit,
    float* __restrict__ out)
{
    const float* w_inT = ws;
    const float* w_out = ws + 4096;
    const float* cb2   = ws + 8192;

    int blk   = blockIdx.x;        // 0..1023
    int b     = blk >> 6;
    int chunk = blk & 63;
    int t     = chunk * 64 + threadIdx.x;

    const float* zp = z + (size_t)b * DIN * TT + t;

    // ---- in-projection: z_e[c] = sum_d w_in[c,d] * z[b,d,t]  (+bias after) ----
    float ze[DCB];
    #pragma unroll
    for (int c = 0; c < DCB; ++c) ze[c] = 0.f;

    #pragma unroll 8
    for (int d = 0; d < DIN; ++d) {
        float zv = zp[(size_t)d * TT];          // coalesced across lanes
        const float* w = w_inT + d * DCB;       // wave-uniform -> s_load
        #pragma unroll
        for (int c = 0; c < DCB; ++c) ze[c] = fmaf(w[c], zv, ze[c]);
    }
    #pragma unroll
    for (int c = 0; c < DCB; ++c) ze[c] += in_b[c];

    // ---- codebook argmin: d = (|enc|^2 - 2 enc.cb) + |cb|^2, first-min wins ----
    float enc2 = 0.f;
    #pragma unroll
    for (int c = 0; c < DCB; ++c) enc2 += ze[c] * ze[c];

    float best = 3.4e38f;
    int   bi   = 0;
    #pragma unroll 4
    for (int k = 0; k < KC; ++k) {
        const float* r = cb + k * DCB;          // wave-uniform -> s_load_dwordx8
        float dot = 0.f;
        #pragma unroll
        for (int c = 0; c < DCB; ++c) dot = fmaf(ze[c], r[c], dot);
        float dk = (enc2 - 2.0f * dot) + cb2[k];
        if (dk < best) { best = dk; bi = k; }
    }

    // ---- z_q gather, straight-through value, commit loss ----
    const float* cq = cb + (size_t)bi * DCB;    // divergent (L1/L2 hit)
    float zst[DCB];
    float cl = 0.f;
    #pragma unroll
    for (int c = 0; c < DCB; ++c) {
        float q    = cq[c];
        float diff = ze[c] - q;
        cl = fmaf(diff, diff, cl);
        zst[c] = ze[c] + (q - ze[c]);           // mimic z_e + stopgrad(z_q - z_e)
    }
    #pragma unroll
    for (int off = 32; off > 0; off >>= 1) cl += __shfl_xor(cl, off, 64);
    if (threadIdx.x == 0) ws_commit[blk] = cl;

    // ---- out-projection: out[b,o,t] = w_out[o,:].zst + out_b[o] ----
    float* outp = out + (size_t)b * DIN * TT + t;
    #pragma unroll 4
    for (int o = 0; o < DIN; ++o) {
        const float* w = w_out + o * DCB;       // wave-uniform -> s_load
        float acc = 0.f;
        #pragma unroll
        for (int c = 0; c < DCB; ++c) acc = fmaf(w[c], zst[c], acc);
        outp[(size_t)o * TT] = acc + out_b[o];  // coalesced store
    }

    // ---- indices (written as float; harness reads buffer as fp32) ----
    out[(size_t)NB * DIN * TT + NB + (size_t)b * TT + t] = (float)bi;
}

__global__ __launch_bounds__(64) void vq_commit(
    const float* __restrict__ ws_commit, float* __restrict__ out)
{
    int b    = blockIdx.x;
    int lane = threadIdx.x;
    float s = ws_commit[b * 64 + lane];
    #pragma unroll
    for (int off = 32; off > 0; off >>= 1) s += __shfl_xor(s, off, 64);
    if (lane == 0)
        out[(size_t)NB * DIN * TT + b] = s * (1.0f / (DCB * TT));
}

extern "C" void kernel_launch(void* const* d_in, const int* in_sizes, int n_in,
                              void* d_out, int out_size, void* d_ws, size_t ws_size,
                              hipStream_t stream) {
    const float* z     = (const float*)d_in[0];
    const float* in_v  = (const float*)d_in[1];
    const float* in_g  = (const float*)d_in[2];
    const float* in_b  = (const float*)d_in[3];
    const float* out_v = (const float*)d_in[4];
    const float* out_g = (const float*)d_in[5];
    const float* out_b = (const float*)d_in[6];
    const float* cb    = (const float*)d_in[7];

    float* ws  = (float*)d_ws;
    float* out = (float*)d_out;

    vq_setup<<<1, 512, 0, stream>>>(in_v, in_g, out_v, out_g, cb, ws);
    vq_main<<<1024, 64, 0, stream>>>(z, in_b, out_b, cb, ws, ws + 9216, out);
    vq_commit<<<NB, 64, 0, stream>>>(ws + 9216, out);
}

// Round 2
// 154.231 us; speedup vs baseline: 1.4365x; 1.4365x over previous
//
#include <hip/hip_runtime.h>
#include <math.h>

#define NB 16
#define DIN 512
#define TT 4096
#define DCB 8
#define KC 1024
#define NW 4            // waves per block

// ws layout (floats):
// [0,4096)      w_inT[d][c]   (transposed)
// [4096,8192)   w_out[o][c]
// [8192,9216)   cb2[k]
// [9216,10240)  per-block commit partials (1024)

__global__ __launch_bounds__(512) void vq_setup(
    const float* __restrict__ in_v, const float* __restrict__ in_g,
    const float* __restrict__ out_v, const float* __restrict__ out_g,
    const float* __restrict__ cb, float* __restrict__ ws)
{
    int tid = threadIdx.x;
    float* w_inT = ws;
    float* w_out = ws + 4096;
    float* cb2   = ws + 8192;

    // --- w_in: 8 rows of 512; one wave per row ---
    {
        int c    = tid >> 6;
        int lane = tid & 63;
        const float* v = in_v + c * DIN;
        float s = 0.f;
        #pragma unroll
        for (int i = 0; i < DIN; i += 64) {
            float x = v[i + lane];
            s += x * x;
        }
        #pragma unroll
        for (int off = 32; off > 0; off >>= 1) s += __shfl_xor(s, off, 64);
        float sq = sqrtf(s);
        float g  = in_g[c];
        #pragma unroll
        for (int i = 0; i < DIN; i += 64) {
            int d = i + lane;
            w_inT[d * DCB + c] = (g * v[d]) / sq;
        }
    }
    // --- w_out: 512 rows of 8 ---
    {
        int o = tid;
        const float* v = out_v + o * DCB;
        float s = 0.f;
        #pragma unroll
        for (int c = 0; c < DCB; ++c) s += v[c] * v[c];
        float sq = sqrtf(s);
        float g  = out_g[o];
        #pragma unroll
        for (int c = 0; c < DCB; ++c) w_out[o * DCB + c] = (g * v[c]) / sq;
    }
    // --- cb2 ---
    for (int k = tid; k < KC; k += 512) {
        const float* r = cb + k * DCB;
        float s = 0.f;
        #pragma unroll
        for (int c = 0; c < DCB; ++c) s += r[c] * r[c];
        cb2[k] = s;
    }
}

__global__ __launch_bounds__(256) void vq_main(
    const float* __restrict__ z, const float* __restrict__ in_b,
    const float* __restrict__ out_b, const float* __restrict__ cb,
    const float* __restrict__ ws, float* __restrict__ ws_commit,
    float* __restrict__ out)
{
    const float* w_inT = ws;
    const float* w_out = ws + 4096;
    const float* cb2   = ws + 8192;

    __shared__ float red[DCB][NW][64];   // 8 KB
    __shared__ float sd[NW][64];
    __shared__ int   si[NW][64];

    int w    = threadIdx.x >> 6;         // 0..3
    int lane = threadIdx.x & 63;
    int blk  = blockIdx.x;               // 0..1023
    int b    = blk >> 6;
    int t    = (blk & 63) * 64 + lane;

    const float* zp = z + (size_t)b * DIN * TT + t;

    // ---- partial in-projection over d in [w*128, w*128+128) ----
    float ze[DCB];
    #pragma unroll
    for (int c = 0; c < DCB; ++c) ze[c] = 0.f;

    int d0 = w * 128;
    #pragma unroll 8
    for (int dd = 0; dd < 128; ++dd) {
        int d = d0 + dd;
        float zv = zp[(size_t)d * TT];       // coalesced across lanes
        const float* wi = w_inT + d * DCB;   // wave-uniform -> s_load
        #pragma unroll
        for (int c = 0; c < DCB; ++c) ze[c] = fmaf(wi[c], zv, ze[c]);
    }

    // ---- cross-wave reduce of ze ----
    #pragma unroll
    for (int c = 0; c < DCB; ++c) red[c][w][lane] = ze[c];
    __syncthreads();
    #pragma unroll
    for (int c = 0; c < DCB; ++c)
        ze[c] = ((red[c][0][lane] + red[c][1][lane]) +
                 (red[c][2][lane] + red[c][3][lane])) + in_b[c];

    // ---- codebook partial argmin over k in [w*256, w*256+256) ----
    float enc2 = 0.f;
    #pragma unroll
    for (int c = 0; c < DCB; ++c) enc2 += ze[c] * ze[c];

    float best = 3.4e38f;
    int   bi   = 0;
    int   k0   = w * 256;
    #pragma unroll 8
    for (int kk = 0; kk < 256; ++kk) {
        int k = k0 + kk;
        const float* r = cb + k * DCB;       // wave-uniform -> s_load_dwordx8
        float dot = 0.f;
        #pragma unroll
        for (int c = 0; c < DCB; ++c) dot = fmaf(ze[c], r[c], dot);
        float dk = (enc2 - 2.0f * dot) + cb2[k];
        if (dk < best) { best = dk; bi = k; }
    }
    sd[w][lane] = best;
    si[w][lane] = bi;
    __syncthreads();

    // ordered combine (w'=0..3, strict < keeps first min over k)
    float gbest = sd[0][lane];
    int   gbi   = si[0][lane];
    #pragma unroll
    for (int w2 = 1; w2 < NW; ++w2) {
        float d2 = sd[w2][lane];
        int   i2 = si[w2][lane];
        if (d2 < gbest) { gbest = d2; gbi = i2; }
    }

    // ---- z_q gather, straight-through value, commit loss ----
    const float* cq = cb + (size_t)gbi * DCB;
    float zst[DCB];
    float cl = 0.f;
    #pragma unroll
    for (int c = 0; c < DCB; ++c) {
        float q    = cq[c];
        float diff = ze[c] - q;
        cl = fmaf(diff, diff, cl);
        zst[c] = ze[c] + (q - ze[c]);        // match z_e + stopgrad(z_q - z_e)
    }
    if (w == 0) {
        #pragma unroll
        for (int off = 32; off > 0; off >>= 1) cl += __shfl_xor(cl, off, 64);
        if (lane == 0) ws_commit[blk] = cl;
        // indices (as float; whole out buffer is read as fp32)
        out[(size_t)NB * DIN * TT + NB + (size_t)b * TT + t] = (float)gbi;
    }

    // ---- out-projection over o in [w*128, w*128+128) ----
    float* outp = out + (size_t)b * DIN * TT + t;
    int o0 = w * 128;
    #pragma unroll 4
    for (int oo = 0; oo < 128; ++oo) {
        int o = o0 + oo;
        const float* wo = w_out + o * DCB;   // wave-uniform -> s_load
        float acc = 0.f;
        #pragma unroll
        for (int c = 0; c < DCB; ++c) acc = fmaf(wo[c], zst[c], acc);
        outp[(size_t)o * TT] = acc + out_b[o];
    }
}

__global__ __launch_bounds__(64) void vq_commit(
    const float* __restrict__ ws_commit, float* __restrict__ out)
{
    int b    = blockIdx.x;
    int lane = threadIdx.x;
    float s = ws_commit[b * 64 + lane];
    #pragma unroll
    for (int off = 32; off > 0; off >>= 1) s += __shfl_xor(s, off, 64);
    if (lane == 0)
        out[(size_t)NB * DIN * TT + b] = s * (1.0f / (DCB * TT));
}

extern "C" void kernel_launch(void* const* d_in, const int* in_sizes, int n_in,
                              void* d_out, int out_size, void* d_ws, size_t ws_size,
                              hipStream_t stream) {
    const float* z     = (const float*)d_in[0];
    const float* in_v  = (const float*)d_in[1];
    const float* in_g  = (const float*)d_in[2];
    const float* in_b  = (const float*)d_in[3];
    const float* out_v = (const float*)d_in[4];
    const float* out_g = (const float*)d_in[5];
    const float* out_b = (const float*)d_in[6];
    const float* cb    = (const float*)d_in[7];

    float* ws  = (float*)d_ws;
    float* out = (float*)d_out;

    vq_setup<<<1, 512, 0, stream>>>(in_v, in_g, out_v, out_g, cb, ws);
    vq_main<<<1024, 256, 0, stream>>>(z, in_b, out_b, cb, ws, ws + 9216, out);
    vq_commit<<<NB, 64, 0, stream>>>(ws + 9216, out);
}